// Round 6
// baseline (155.601 us; speedup 1.0000x reference)
//
#include <hip/hip_runtime.h>
#include <math.h>

#define B_ROWS 4096
#define D_DIM  1024
static constexpr float TEMP = 0.2f;
static constexpr float FP8_SCALE = 16.0f;        // per-side scale before cast
static constexpr float INV_S2 = 1.0f / 256.0f;   // 1/SCALE^2: acc -> sim

typedef __attribute__((ext_vector_type(4)))  int   i32x4;
typedef __attribute__((ext_vector_type(8)))  int   i32x8;
typedef __attribute__((ext_vector_type(4)))  float f32x4;

// float -> OCP e4m3fn byte, RNE. Data path: |f| <= ~4, no NaN/inf.
__device__ inline unsigned char f2fp8(float f) {
    unsigned int u = __float_as_uint(f);
    unsigned int s = (u >> 24) & 0x80u;
    float af = fabsf(f);
    unsigned char b;
    if (af >= 0x1.0p-6f) {                 // normal e4m3 range
        unsigned int au = u & 0x7fffffffu;
        unsigned int lsb = (au >> 20) & 1u;
        au += 0x7ffffu + lsb;              // RNE into 3 mantissa bits
        int e = (int)(au >> 23) - 127 + 7;
        unsigned int m = (au >> 20) & 7u;
        if (e > 15 || (e == 15 && m > 6)) b = 0x7e;   // saturate 448
        else b = (unsigned char)((e << 3) | m);
    } else {                               // subnormal: quantum 2^-9
        int q = (int)rintf(af * 512.0f);
        b = (unsigned char)(q >= 8 ? 0x08 : q);
    }
    return (unsigned char)(b | s);
}

__device__ inline unsigned int f2fp8x4(float4 v) {
    return (unsigned int)f2fp8(v.x)
         | ((unsigned int)f2fp8(v.y) << 8)
         | ((unsigned int)f2fp8(v.z) << 16)
         | ((unsigned int)f2fp8(v.w) << 24);
}

// async global->LDS, 16 B/lane; LDS dest = wave-uniform base + lane*16
__device__ inline void gload_lds16(const unsigned char* g, unsigned char* l) {
    __builtin_amdgcn_global_load_lds(
        (const __attribute__((address_space(1))) unsigned int*)g,
        (__attribute__((address_space(3))) unsigned int*)l,
        16, 0, 0);
}

// read one 32-B fragment (two swizzled 16-B pieces) -> v8i32 MFMA operand
__device__ inline i32x8 read_frag(const unsigned char* p, int o0, int o1) {
    i32x4 lo = *(const i32x4*)(p + o0);
    i32x4 hi = *(const i32x4*)(p + o1);
    return __builtin_shufflevector(lo, hi, 0, 1, 2, 3, 4, 5, 6, 7);
}

// MX-scaled fp8 x fp8, K=128, unit E8M0 scales (0x7f = 2^0): fp8 GEMM at 2x
// rate with f32x4 accumulator (proven clean-alloc in round 4; the 32x32x64
// f32x16-acc form spilled ~300 MB scratch in rounds 1-3).
#define MX_MFMA(A, Bv, C) __builtin_amdgcn_mfma_scale_f32_16x16x128_f8f6f4( \
    (A), (Bv), (C), 0, 0, 0, 0x7f7f7f7f, 0, 0x7f7f7f7f)

// ws layout: w[0]=pos acc, w[1]=neg acc, w[2]=finalize ticket (u32),
//            then Zi8 (4096x1024 fp8) at byte (w+16), Zj8 after.

// Wave-per-row normalize (fp32) + scale by 16 + cast to fp8 e4m3.
__global__ __launch_bounds__(256) void norm_cast_kernel(
        const float* __restrict__ emb_i, const float* __restrict__ emb_j,
        unsigned char* __restrict__ Zi8, unsigned char* __restrict__ Zj8,
        float* __restrict__ w) {
    const int tid = threadIdx.x;
    if (blockIdx.x == 0 && tid == 0) {
        w[0] = 0.0f; w[1] = 0.0f;
        ((unsigned int*)w)[2] = 0u;
    }
    const int wave = tid >> 6, lane = tid & 63;
    const int row = blockIdx.x * 4 + wave;          // 0..8191
    const float* src; unsigned char* dst; int r;
    if (row < B_ROWS) { src = emb_i; dst = Zi8; r = row; }
    else              { src = emb_j; dst = Zj8; r = row - B_ROWS; }

    const float4* p = (const float4*)(src + (size_t)r * D_DIM);
    float4 v0 = p[lane], v1 = p[64 + lane], v2 = p[128 + lane], v3 = p[192 + lane];
    float s = v0.x*v0.x + v0.y*v0.y + v0.z*v0.z + v0.w*v0.w
            + v1.x*v1.x + v1.y*v1.y + v1.z*v1.z + v1.w*v1.w
            + v2.x*v2.x + v2.y*v2.y + v2.z*v2.z + v2.w*v2.w
            + v3.x*v3.x + v3.y*v3.y + v3.z*v3.z + v3.w*v3.w;
    #pragma unroll
    for (int m = 1; m < 64; m <<= 1) s += __shfl_xor(s, m, 64);
    const float inv = FP8_SCALE / fmaxf(sqrtf(s), 1e-12f);

    float4 a0 = {v0.x*inv, v0.y*inv, v0.z*inv, v0.w*inv};
    float4 a1 = {v1.x*inv, v1.y*inv, v1.z*inv, v1.w*inv};
    float4 a2 = {v2.x*inv, v2.y*inv, v2.z*inv, v2.w*inv};
    float4 a3 = {v3.x*inv, v3.y*inv, v3.z*inv, v3.w*inv};
    unsigned int* q = (unsigned int*)(dst + (size_t)r * D_DIM);
    q[lane]       = f2fp8x4(a0);
    q[64 + lane]  = f2fp8x4(a1);
    q[128 + lane] = f2fp8x4(a2);
    q[192 + lane] = f2fp8x4(a3);
}

// 128x128 block tile, BK=128 bytes (fp8), 4 waves (2x2): wave owns 64x64 =
// 4x4 MFMA tiles of 16x16x128 MX-fp8 (unit scales), ONE K-step per LDS tile.
// Grid 32x32 = 1024 blocks.
//
// T3-minimum pipeline (round-4 fix): DOUBLE-buffered LDS (2 x 32 KB -> still
// 2 blocks/CU), ONE barrier per iteration, and STAGE of tile t+1 issued
// BEFORE the ds_read+MFMA of tile t -- so the barrier's implicit vmcnt(0)
// drain comes after ~400 cycles of compute instead of immediately (round 4
// exposed the full L2 latency every iter: 58.6 us vs 13.7 us pipe floor).
// No fragment is live across a barrier (spill lesson, rounds 1-3).
// Race-free: each __syncthreads drains vmcnt+lgkm, so the staged tile is
// complete before any wave reads it, and the buffer overwritten at t+1 had
// its readers finish before the barrier ending iteration t.
//
// LDS row = 128 B = 8 x 16-B pieces. XOR swizzle: logical piece c of row r sits
// at physical piece p = c ^ (r&7) (involution; numerics verified rounds 1-4).
// global_load_lds writes linearly (lane*16), so the *global* source piece is
// pre-swizzled per lane; LDS stays linear.
__global__ __launch_bounds__(256) void simloss_mfma_mxfp8_kernel(
        const unsigned char* __restrict__ Zi8,
        const unsigned char* __restrict__ Zj8,
        float* __restrict__ w, float* __restrict__ out) {
    __shared__ __align__(16) unsigned char lds[2 * 32768];  // [buf][A:16K|B:16K]
    __shared__ float rn[4], rp[4];

    const int tid  = threadIdx.x;
    const int lane = tid & 63;
    const int wave = tid >> 6;
    const int wy = wave >> 1, wx = wave & 1;
    const int rowBase = blockIdx.y * 128;   // a (Zj rows)
    const int colBase = blockIdx.x * 128;   // b (Zi rows)

    // --- staging: chunk = 8 rows x 128 B = 1 KB = one wave-load (16 B/lane).
    //     lane l -> LDS row (l>>3), physical piece (l&7); needs logical piece
    //     c = (l&7) ^ (row&7) = (l&7) ^ (l>>3) from global.
    //     Wave w stages A rows [32w, 32w+32) and B rows [32w, 32w+32).
    const int srow = lane >> 3;
    const int sc   = (lane & 7) ^ srow;
    const unsigned char* gA = Zj8 + (size_t)(rowBase + 32*wave + srow) * D_DIM + sc*16;
    const unsigned char* gB = Zi8 + (size_t)(colBase + 32*wave + srow) * D_DIM + sc*16;
    const int sAoff = wave * 4096;            // A region: buf + [0, 16K)
    const int sBoff = 16384 + wave * 4096;    // B region: buf + [16K, 32K)

#define STAGE(k0, bo) do {                                                     \
        _Pragma("unroll")                                                      \
        for (int n = 0; n < 4; ++n) {                                          \
            gload_lds16(gA + (size_t)(n*8) * D_DIM + (k0),                     \
                        lds + (bo) + sAoff + n*1024);                          \
            gload_lds16(gB + (size_t)(n*8) * D_DIM + (k0),                     \
                        lds + (bo) + sBoff + n*1024);                          \
        }                                                                      \
    } while (0)

    // --- fragment addressing (16x16x128): lane l holds row (l&15),
    //     k = (l>>4)*32 + 0..31 -> logical pieces {2g, 2g+1}, g = l>>4.
    //     physical = logical ^ (row&7); row&7 == lane&7 since every fragment
    //     row base (wy*64 + i*16) is a multiple of 8 and row = base + (l&15).
    const int lr16 = lane & 15;
    const int g    = lane >> 4;
    const int o0 = ((((g << 1) + 0) ^ (lane & 7)) << 4);
    const int o1 = ((((g << 1) + 1) ^ (lane & 7)) << 4);
    const int fAoff = (wy * 64 + lr16) * 128;          // + i*16*128, in A region
    const int fBoff = 16384 + (wx * 64 + lr16) * 128;  // + j*16*128, in B region

    f32x4 acc[4][4];
    #pragma unroll
    for (int i = 0; i < 4; ++i)
        #pragma unroll
        for (int j = 0; j < 4; ++j)
            acc[i][j] = (f32x4){0.f, 0.f, 0.f, 0.f};

    STAGE(0, 0);
    __syncthreads();                        // prologue tile visible
    int cur = 0;
    for (int it = 0; it < 8; ++it) {
        if (it < 7) STAGE((it + 1) * 128, cur ^ 32768);  // loads fly under MFMA

        const unsigned char* fA = lds + cur + fAoff;
        const unsigned char* fB = lds + cur + fBoff;
        i32x8 a0 = read_frag(fA,        o0, o1);
        i32x8 a1 = read_frag(fA + 2048, o0, o1);
        i32x8 a2 = read_frag(fA + 4096, o0, o1);
        i32x8 a3 = read_frag(fA + 6144, o0, o1);
        i32x8 b0 = read_frag(fB,        o0, o1);
        i32x8 b1 = read_frag(fB + 2048, o0, o1);
        i32x8 b2 = read_frag(fB + 4096, o0, o1);
        i32x8 b3 = read_frag(fB + 6144, o0, o1);
        acc[0][0] = MX_MFMA(a0, b0, acc[0][0]);
        acc[0][1] = MX_MFMA(a0, b1, acc[0][1]);
        acc[0][2] = MX_MFMA(a0, b2, acc[0][2]);
        acc[0][3] = MX_MFMA(a0, b3, acc[0][3]);
        acc[1][0] = MX_MFMA(a1, b0, acc[1][0]);
        acc[1][1] = MX_MFMA(a1, b1, acc[1][1]);
        acc[1][2] = MX_MFMA(a1, b2, acc[1][2]);
        acc[1][3] = MX_MFMA(a1, b3, acc[1][3]);
        acc[2][0] = MX_MFMA(a2, b0, acc[2][0]);
        acc[2][1] = MX_MFMA(a2, b1, acc[2][1]);
        acc[2][2] = MX_MFMA(a2, b2, acc[2][2]);
        acc[2][3] = MX_MFMA(a2, b3, acc[2][3]);
        acc[3][0] = MX_MFMA(a3, b0, acc[3][0]);
        acc[3][1] = MX_MFMA(a3, b1, acc[3][1]);
        acc[3][2] = MX_MFMA(a3, b2, acc[3][2]);
        acc[3][3] = MX_MFMA(a3, b3, acc[3][3]);

        __syncthreads();    // drains vmcnt: next tile ready; readers done
        cur ^= 32768;
    }
#undef STAGE

    // --- fused epilogue; 16x16 C layout: col=lane&15, row=(lane>>4)*4+reg
    //     (round-0-verified mapping)
    float neg = 0.f, pos = 0.f;
    const int bc = colBase + wx * 64 + lr16;
    #pragma unroll
    for (int i = 0; i < 4; ++i) {
        const int abase = rowBase + wy * 64 + i * 16 + g * 4;
        #pragma unroll
        for (int j = 0; j < 4; ++j) {
            const int b = bc + j * 16;
            #pragma unroll
            for (int r = 0; r < 4; ++r) {
                const float x = acc[i][j][r] * INV_S2 - TEMP;   // sim - T
                if (abase + r == b) pos += __logf(1.0f + __expf(-x));
                else                neg += __logf(1.0f + __expf(x));
            }
        }
    }
    #pragma unroll
    for (int o = 32; o > 0; o >>= 1) {
        neg += __shfl_down(neg, o, 64);
        pos += __shfl_down(pos, o, 64);
    }
    if (lane == 0) { rn[wave] = neg; rp[wave] = pos; }
    __syncthreads();
    if (tid == 0) {
        atomicAdd(&w[1], rn[0] + rn[1] + rn[2] + rn[3]);
        if (blockIdx.x == blockIdx.y)                    // tile holding diagonal
            atomicAdd(&w[0], rp[0] + rp[1] + rp[2] + rp[3]);
        __threadfence();
        unsigned int done = atomicAdd(((unsigned int*)w) + 2, 1u);
        if (done == gridDim.x * gridDim.y - 1) {         // last block finalizes
            const float psum = atomicAdd(&w[0], 0.0f);
            const float nsum = atomicAdd(&w[1], 0.0f);
            out[0] = 0.5f * (psum / (float)B_ROWS)
                   + 0.5f * (nsum / ((float)B_ROWS * (float)(B_ROWS - 1)));
        }
    }
}

extern "C" void kernel_launch(void* const* d_in, const int* in_sizes, int n_in,
                              void* d_out, int out_size, void* d_ws, size_t ws_size,
                              hipStream_t stream) {
    const float* emb_i = (const float*)d_in[0];
    const float* emb_j = (const float*)d_in[1];
    float* w = (float*)d_ws;
    unsigned char* Zi8 = (unsigned char*)(w + 16);
    unsigned char* Zj8 = Zi8 + (size_t)B_ROWS * D_DIM;
    float* out = (float*)d_out;

    norm_cast_kernel<<<2 * B_ROWS / 4, 256, 0, stream>>>(emb_i, emb_j, Zi8, Zj8, w);
    dim3 grid(B_ROWS / 128, B_ROWS / 128);   // 32 x 32 = 1024 blocks
    simloss_mfma_mxfp8_kernel<<<grid, 256, 0, stream>>>(Zi8, Zj8, w, out);
}

// Round 7
// 129.865 us; speedup vs baseline: 1.1982x; 1.1982x over previous
//
#include <hip/hip_runtime.h>
#include <math.h>

#define B_ROWS 4096
#define D_DIM  1024
static constexpr float TEMP = 0.2f;
static constexpr float FP8_SCALE = 16.0f;        // per-side scale before cast
static constexpr float INV_S2 = 1.0f / 256.0f;   // 1/SCALE^2: acc -> sim

typedef __attribute__((ext_vector_type(4)))  int   i32x4;
typedef __attribute__((ext_vector_type(8)))  int   i32x8;
typedef __attribute__((ext_vector_type(4)))  float f32x4;

// float -> OCP e4m3fn byte, RNE. Data path: |f| <= ~4, no NaN/inf.
__device__ inline unsigned char f2fp8(float f) {
    unsigned int u = __float_as_uint(f);
    unsigned int s = (u >> 24) & 0x80u;
    float af = fabsf(f);
    unsigned char b;
    if (af >= 0x1.0p-6f) {                 // normal e4m3 range
        unsigned int au = u & 0x7fffffffu;
        unsigned int lsb = (au >> 20) & 1u;
        au += 0x7ffffu + lsb;              // RNE into 3 mantissa bits
        int e = (int)(au >> 23) - 127 + 7;
        unsigned int m = (au >> 20) & 7u;
        if (e > 15 || (e == 15 && m > 6)) b = 0x7e;   // saturate 448
        else b = (unsigned char)((e << 3) | m);
    } else {                               // subnormal: quantum 2^-9
        int q = (int)rintf(af * 512.0f);
        b = (unsigned char)(q >= 8 ? 0x08 : q);
    }
    return (unsigned char)(b | s);
}

__device__ inline unsigned int f2fp8x4(float4 v) {
    return (unsigned int)f2fp8(v.x)
         | ((unsigned int)f2fp8(v.y) << 8)
         | ((unsigned int)f2fp8(v.z) << 16)
         | ((unsigned int)f2fp8(v.w) << 24);
}

// async global->LDS, 16 B/lane; LDS dest = wave-uniform base + lane*16
__device__ inline void gload_lds16(const unsigned char* g, unsigned char* l) {
    __builtin_amdgcn_global_load_lds(
        (const __attribute__((address_space(1))) unsigned int*)g,
        (__attribute__((address_space(3))) unsigned int*)l,
        16, 0, 0);
}

// read one 32-B fragment (two swizzled 16-B pieces) -> v8i32 MFMA operand
__device__ inline i32x8 read_frag(const unsigned char* p, int o0, int o1) {
    i32x4 lo = *(const i32x4*)(p + o0);
    i32x4 hi = *(const i32x4*)(p + o1);
    return __builtin_shufflevector(lo, hi, 0, 1, 2, 3, 4, 5, 6, 7);
}

// MX-scaled fp8 x fp8, K=128, unit E8M0 scales (0x7f = 2^0): fp8 GEMM at 2x
// rate with f32x4 accumulator (proven clean-alloc in round 4; the 32x32x64
// f32x16-acc form spilled ~300 MB scratch in rounds 1-3).
#define MX_MFMA(A, Bv, C) __builtin_amdgcn_mfma_scale_f32_16x16x128_f8f6f4( \
    (A), (Bv), (C), 0, 0, 0, 0x7f7f7f7f, 0, 0x7f7f7f7f)

// ws layout: w[0]=pos acc, w[1]=neg acc, w[2]=finalize ticket (u32),
//            then Zi8 (4096x1024 fp8) at byte (w+16), Zj8 after.

// Wave-per-row normalize (fp32) + scale by 16 + cast to fp8 e4m3.
__global__ __launch_bounds__(256) void norm_cast_kernel(
        const float* __restrict__ emb_i, const float* __restrict__ emb_j,
        unsigned char* __restrict__ Zi8, unsigned char* __restrict__ Zj8,
        float* __restrict__ w) {
    const int tid = threadIdx.x;
    if (blockIdx.x == 0 && tid == 0) {
        w[0] = 0.0f; w[1] = 0.0f;
        ((unsigned int*)w)[2] = 0u;
    }
    const int wave = tid >> 6, lane = tid & 63;
    const int row = blockIdx.x * 4 + wave;          // 0..8191
    const float* src; unsigned char* dst; int r;
    if (row < B_ROWS) { src = emb_i; dst = Zi8; r = row; }
    else              { src = emb_j; dst = Zj8; r = row - B_ROWS; }

    const float4* p = (const float4*)(src + (size_t)r * D_DIM);
    float4 v0 = p[lane], v1 = p[64 + lane], v2 = p[128 + lane], v3 = p[192 + lane];
    float s = v0.x*v0.x + v0.y*v0.y + v0.z*v0.z + v0.w*v0.w
            + v1.x*v1.x + v1.y*v1.y + v1.z*v1.z + v1.w*v1.w
            + v2.x*v2.x + v2.y*v2.y + v2.z*v2.z + v2.w*v2.w
            + v3.x*v3.x + v3.y*v3.y + v3.z*v3.z + v3.w*v3.w;
    #pragma unroll
    for (int m = 1; m < 64; m <<= 1) s += __shfl_xor(s, m, 64);
    const float inv = FP8_SCALE / fmaxf(sqrtf(s), 1e-12f);

    float4 a0 = {v0.x*inv, v0.y*inv, v0.z*inv, v0.w*inv};
    float4 a1 = {v1.x*inv, v1.y*inv, v1.z*inv, v1.w*inv};
    float4 a2 = {v2.x*inv, v2.y*inv, v2.z*inv, v2.w*inv};
    float4 a3 = {v3.x*inv, v3.y*inv, v3.z*inv, v3.w*inv};
    unsigned int* q = (unsigned int*)(dst + (size_t)r * D_DIM);
    q[lane]       = f2fp8x4(a0);
    q[64 + lane]  = f2fp8x4(a1);
    q[128 + lane] = f2fp8x4(a2);
    q[192 + lane] = f2fp8x4(a3);
}

// 128x128 block tile, BK=128 bytes (fp8), 4 waves (2x2): wave owns 64x64 =
// 4x4 MFMA tiles of 16x16x128 MX-fp8 (unit scales), ONE K-step per LDS tile.
// ROUND-4 SKELETON (proven: VGPR 92, 4 blocks/CU, absmax 0.0) + T1 XCD
// swizzle. Round 6 showed pipelining is not the lever: staging throughput is
// pinned at ~4 TB/s regardless of schedule -> L2-locality-bound (each XCD's
// default working set ~8 MB > 4 MB L2; 256 MB logical re-reads served by
// L3/fabric).
//
// T1: 1D grid 1024; bid%8 = XCD (round-robin dispatch). Each XCD owns a
// 16(row) x 8(col) rectangle of the 32x32 tile grid: working set = 16 A-panels
// (2 MB) + 8 B-panels (1 MB) = 3 MB < 4 MB per-XCD L2. At 4 blocks/CU the
// whole 1024-block grid is co-resident, so each XCD's panels stay L2-live for
// the entire kernel. Bijection: (by,bx) = ((xcd>>2)*16 + loc/8,
// (xcd&3)*8 + loc%8), loc = bid>>3.
//
// LDS row = 128 B = 8 x 16-B pieces. XOR swizzle: logical piece c of row r sits
// at physical piece p = c ^ (r&7) (involution; numerics verified rounds 1-6).
// global_load_lds writes linearly (lane*16), so the *global* source piece is
// pre-swizzled per lane; LDS stays linear.
__global__ __launch_bounds__(256) void simloss_mfma_mxfp8_kernel(
        const unsigned char* __restrict__ Zi8,
        const unsigned char* __restrict__ Zj8,
        float* __restrict__ w, float* __restrict__ out) {
    __shared__ __align__(16) unsigned char lA[128 * 128];  // 16 KB (Zj rows)
    __shared__ __align__(16) unsigned char lB[128 * 128];  // 16 KB (Zi rows)
    __shared__ float rn[4], rp[4];

    const int tid  = threadIdx.x;
    const int lane = tid & 63;
    const int wave = tid >> 6;
    const int wy = wave >> 1, wx = wave & 1;

    // --- T1 XCD-rectangle swizzle (bijective on 32x32)
    const int bid = blockIdx.x;             // 0..1023
    const int xcd = bid & 7;
    const int loc = bid >> 3;               // 0..127
    const int by  = ((xcd >> 2) << 4) + (loc >> 3);   // 0..31
    const int bx  = ((xcd & 3) << 3) + (loc & 7);     // 0..31
    const int rowBase = by * 128;           // a (Zj rows)
    const int colBase = bx * 128;           // b (Zi rows)

    // --- staging: chunk = 8 rows x 128 B = 1 KB = one wave-load (16 B/lane).
    //     lane l -> LDS row (l>>3), physical piece (l&7); needs logical piece
    //     c = (l&7) ^ (row&7) = (l&7) ^ (l>>3) from global.
    //     Wave w stages A rows [32w, 32w+32) and B rows [32w, 32w+32).
    const int srow = lane >> 3;
    const int sc   = (lane & 7) ^ srow;
    const unsigned char* gA = Zj8 + (size_t)(rowBase + 32*wave + srow) * D_DIM + sc*16;
    const unsigned char* gB = Zi8 + (size_t)(colBase + 32*wave + srow) * D_DIM + sc*16;
    unsigned char* sA = lA + wave * 4096;
    unsigned char* sB = lB + wave * 4096;

    // --- fragment addressing (16x16x128): lane l holds row (l&15),
    //     k = (l>>4)*32 + 0..31 -> logical pieces {2g, 2g+1}, g = l>>4.
    //     physical = logical ^ (row&7); row&7 == lane&7 since every fragment
    //     row base (wy*64 + i*16) is a multiple of 8 and row = base + (l&15).
    const int lr16 = lane & 15;
    const int g    = lane >> 4;
    const int o0 = ((((g << 1) + 0) ^ (lane & 7)) << 4);
    const int o1 = ((((g << 1) + 1) ^ (lane & 7)) << 4);
    const unsigned char* fA = lA + (wy * 64 + lr16) * 128;  // + i*16*128
    const unsigned char* fB = lB + (wx * 64 + lr16) * 128;  // + j*16*128

    f32x4 acc[4][4];
    #pragma unroll
    for (int i = 0; i < 4; ++i)
        #pragma unroll
        for (int j = 0; j < 4; ++j)
            acc[i][j] = (f32x4){0.f, 0.f, 0.f, 0.f};

    for (int it = 0; it < 8; ++it) {
        __syncthreads();                    // prior readers done
        const int k0 = it * 128;
        #pragma unroll
        for (int n = 0; n < 4; ++n) {
            gload_lds16(gA + (size_t)(n*8) * D_DIM + k0, sA + n*1024);
            gload_lds16(gB + (size_t)(n*8) * D_DIM + k0, sB + n*1024);
        }
        __syncthreads();                    // staging visible (vmcnt drained)

        i32x8 a0 = read_frag(fA,        o0, o1);
        i32x8 a1 = read_frag(fA + 2048, o0, o1);
        i32x8 a2 = read_frag(fA + 4096, o0, o1);
        i32x8 a3 = read_frag(fA + 6144, o0, o1);
        i32x8 b0 = read_frag(fB,        o0, o1);
        i32x8 b1 = read_frag(fB + 2048, o0, o1);
        i32x8 b2 = read_frag(fB + 4096, o0, o1);
        i32x8 b3 = read_frag(fB + 6144, o0, o1);
        acc[0][0] = MX_MFMA(a0, b0, acc[0][0]);
        acc[0][1] = MX_MFMA(a0, b1, acc[0][1]);
        acc[0][2] = MX_MFMA(a0, b2, acc[0][2]);
        acc[0][3] = MX_MFMA(a0, b3, acc[0][3]);
        acc[1][0] = MX_MFMA(a1, b0, acc[1][0]);
        acc[1][1] = MX_MFMA(a1, b1, acc[1][1]);
        acc[1][2] = MX_MFMA(a1, b2, acc[1][2]);
        acc[1][3] = MX_MFMA(a1, b3, acc[1][3]);
        acc[2][0] = MX_MFMA(a2, b0, acc[2][0]);
        acc[2][1] = MX_MFMA(a2, b1, acc[2][1]);
        acc[2][2] = MX_MFMA(a2, b2, acc[2][2]);
        acc[2][3] = MX_MFMA(a2, b3, acc[2][3]);
        acc[3][0] = MX_MFMA(a3, b0, acc[3][0]);
        acc[3][1] = MX_MFMA(a3, b1, acc[3][1]);
        acc[3][2] = MX_MFMA(a3, b2, acc[3][2]);
        acc[3][3] = MX_MFMA(a3, b3, acc[3][3]);
    }

    // --- fused epilogue; 16x16 C layout: col=lane&15, row=(lane>>4)*4+reg
    //     (round-0-verified mapping)
    float neg = 0.f, pos = 0.f;
    const int bc = colBase + wx * 64 + lr16;
    #pragma unroll
    for (int i = 0; i < 4; ++i) {
        const int abase = rowBase + wy * 64 + i * 16 + g * 4;
        #pragma unroll
        for (int j = 0; j < 4; ++j) {
            const int b = bc + j * 16;
            #pragma unroll
            for (int r = 0; r < 4; ++r) {
                const float x = acc[i][j][r] * INV_S2 - TEMP;   // sim - T
                if (abase + r == b) pos += __logf(1.0f + __expf(-x));
                else                neg += __logf(1.0f + __expf(x));
            }
        }
    }
    #pragma unroll
    for (int o = 32; o > 0; o >>= 1) {
        neg += __shfl_down(neg, o, 64);
        pos += __shfl_down(pos, o, 64);
    }
    if (lane == 0) { rn[wave] = neg; rp[wave] = pos; }
    __syncthreads();
    if (tid == 0) {
        atomicAdd(&w[1], rn[0] + rn[1] + rn[2] + rn[3]);
        if (bx == by)                                    // tile holding diagonal
            atomicAdd(&w[0], rp[0] + rp[1] + rp[2] + rp[3]);
        __threadfence();
        unsigned int done = atomicAdd(((unsigned int*)w) + 2, 1u);
        if (done == gridDim.x - 1) {                     // last block finalizes
            const float psum = atomicAdd(&w[0], 0.0f);
            const float nsum = atomicAdd(&w[1], 0.0f);
            out[0] = 0.5f * (psum / (float)B_ROWS)
                   + 0.5f * (nsum / ((float)B_ROWS * (float)(B_ROWS - 1)));
        }
    }
}

extern "C" void kernel_launch(void* const* d_in, const int* in_sizes, int n_in,
                              void* d_out, int out_size, void* d_ws, size_t ws_size,
                              hipStream_t stream) {
    const float* emb_i = (const float*)d_in[0];
    const float* emb_j = (const float*)d_in[1];
    float* w = (float*)d_ws;
    unsigned char* Zi8 = (unsigned char*)(w + 16);
    unsigned char* Zj8 = Zi8 + (size_t)B_ROWS * D_DIM;
    float* out = (float*)d_out;

    norm_cast_kernel<<<2 * B_ROWS / 4, 256, 0, stream>>>(emb_i, emb_j, Zi8, Zj8, w);
    simloss_mfma_mxfp8_kernel<<<1024, 256, 0, stream>>>(Zi8, Zj8, w, out);
}

// Round 8
// 126.176 us; speedup vs baseline: 1.2332x; 1.0292x over previous
//
#include <hip/hip_runtime.h>
#include <math.h>

#define B_ROWS 4096
#define D_DIM  1024
static constexpr float TEMP = 0.2f;
static constexpr float FP8_SCALE = 16.0f;        // per-side scale before cast
static constexpr float INV_S2 = 1.0f / 256.0f;   // 1/SCALE^2: acc -> sim

typedef __attribute__((ext_vector_type(4)))  int   i32x4;
typedef __attribute__((ext_vector_type(8)))  int   i32x8;
typedef __attribute__((ext_vector_type(4)))  float f32x4;

// async global->LDS, 16 B/lane; LDS dest = wave-uniform base + lane*16
__device__ inline void gload_lds16(const unsigned char* g, unsigned char* l) {
    __builtin_amdgcn_global_load_lds(
        (const __attribute__((address_space(1))) unsigned int*)g,
        (__attribute__((address_space(3))) unsigned int*)l,
        16, 0, 0);
}

// read one 32-B fragment (two swizzled 16-B pieces) -> v8i32 MFMA operand
__device__ inline i32x8 read_frag(const unsigned char* p, int o0, int o1) {
    i32x4 lo = *(const i32x4*)(p + o0);
    i32x4 hi = *(const i32x4*)(p + o1);
    return __builtin_shufflevector(lo, hi, 0, 1, 2, 3, 4, 5, 6, 7);
}

// MX-scaled fp8 x fp8, K=128, unit E8M0 scales (0x7f = 2^0): fp8 GEMM at 2x
// rate with f32x4 accumulator (proven clean-alloc in rounds 4/7; the 32x32x64
// f32x16-acc form spilled ~300 MB scratch in rounds 1-3).
#define MX_MFMA(A, Bv, C) __builtin_amdgcn_mfma_scale_f32_16x16x128_f8f6f4( \
    (A), (Bv), (C), 0, 0, 0, 0x7f7f7f7f, 0, 0x7f7f7f7f)

// pack 4 floats -> 4 fp8 e4m3fn bytes via HW converter (RNE, saturating):
// two v_cvt_pk_fp8_f32 fill the low and high 16 bits of one dword.
__device__ inline unsigned int cvt4_fp8(float4 v) {
    int d = 0;
    d = __builtin_amdgcn_cvt_pk_fp8_f32(v.x, v.y, d, false);  // bytes 0,1
    d = __builtin_amdgcn_cvt_pk_fp8_f32(v.z, v.w, d, true);   // bytes 2,3
    return (unsigned int)d;
}

// ws layout: w[0]=pos acc, w[1]=neg acc, w[2]=finalize ticket (u32),
//            then Zi8 (4096x1024 fp8) at byte (w+16), Zj8 after.

// Wave-per-row normalize (fp32) + scale by 16 + cast to fp8 e4m3 (HW cvt).
// Round-8 rewrite: lane owns 16 CONTIGUOUS elements (64 B) -> 8 cvt_pk + one
// 16-B store per lane, replacing the ~25-VALU-op/element branchy soft-cvt and
// 4 strided dword stores of rounds 0-7 (suspected ~45-55 us, 6x roofline).
__global__ __launch_bounds__(256) void norm_cast_kernel(
        const float* __restrict__ emb_i, const float* __restrict__ emb_j,
        unsigned char* __restrict__ Zi8, unsigned char* __restrict__ Zj8,
        float* __restrict__ w) {
    const int tid = threadIdx.x;
    if (blockIdx.x == 0 && tid == 0) {
        w[0] = 0.0f; w[1] = 0.0f;
        ((unsigned int*)w)[2] = 0u;
    }
    const int wave = tid >> 6, lane = tid & 63;
    const int row = blockIdx.x * 4 + wave;          // 0..8191
    const float* src; unsigned char* dst; int r;
    if (row < B_ROWS) { src = emb_i; dst = Zi8; r = row; }
    else              { src = emb_j; dst = Zj8; r = row - B_ROWS; }

    // lane reads elements [16*lane, 16*lane+16): 4 float4 at 64-B lane stride;
    // the wave's 4 loads together cover the 4 KB row exactly once.
    const float4* p = (const float4*)(src + (size_t)r * D_DIM) + 4 * lane;
    float4 v0 = p[0], v1 = p[1], v2 = p[2], v3 = p[3];
    float s = v0.x*v0.x + v0.y*v0.y + v0.z*v0.z + v0.w*v0.w
            + v1.x*v1.x + v1.y*v1.y + v1.z*v1.z + v1.w*v1.w
            + v2.x*v2.x + v2.y*v2.y + v2.z*v2.z + v2.w*v2.w
            + v3.x*v3.x + v3.y*v3.y + v3.z*v3.z + v3.w*v3.w;
    #pragma unroll
    for (int m = 1; m < 64; m <<= 1) s += __shfl_xor(s, m, 64);
    const float inv = FP8_SCALE / fmaxf(sqrtf(s), 1e-12f);

    float4 a0 = {v0.x*inv, v0.y*inv, v0.z*inv, v0.w*inv};
    float4 a1 = {v1.x*inv, v1.y*inv, v1.z*inv, v1.w*inv};
    float4 a2 = {v2.x*inv, v2.y*inv, v2.z*inv, v2.w*inv};
    float4 a3 = {v3.x*inv, v3.y*inv, v3.z*inv, v3.w*inv};
    i32x4 o = { (int)cvt4_fp8(a0), (int)cvt4_fp8(a1),
                (int)cvt4_fp8(a2), (int)cvt4_fp8(a3) };
    ((i32x4*)(dst + (size_t)r * D_DIM))[lane] = o;   // 16 B/lane, unit stride
}

// 128x128 block tile, BK=128 bytes (fp8), 4 waves (2x2): wave owns 64x64 =
// 4x4 MFMA tiles of 16x16x128 MX-fp8 (unit scales), ONE K-step per LDS tile.
// ROUND-7 KERNEL UNCHANGED (best measured: 56.7 us, VGPR 92, 4 blocks/CU,
// absmax 0.0). T1 swizzle kept: FETCH 18.5->12.4 MB (locality confirmed);
// time flat -> simloss is internally stall-bound, lever exhausted here.
//
// T1: 1D grid 1024; bid%8 = XCD (round-robin dispatch). Each XCD owns a
// 16(row) x 8(col) rectangle of the 32x32 tile grid: working set 3 MB < 4 MB
// per-XCD L2; whole grid co-resident at 4 blocks/CU.
//
// LDS row = 128 B = 8 x 16-B pieces. XOR swizzle: logical piece c of row r
// sits at physical piece p = c ^ (r&7) (involution; verified rounds 1-7).
// global_load_lds writes linearly (lane*16), so the *global* source piece is
// pre-swizzled per lane; LDS stays linear.
__global__ __launch_bounds__(256) void simloss_mfma_mxfp8_kernel(
        const unsigned char* __restrict__ Zi8,
        const unsigned char* __restrict__ Zj8,
        float* __restrict__ w, float* __restrict__ out) {
    __shared__ __align__(16) unsigned char lA[128 * 128];  // 16 KB (Zj rows)
    __shared__ __align__(16) unsigned char lB[128 * 128];  // 16 KB (Zi rows)
    __shared__ float rn[4], rp[4];

    const int tid  = threadIdx.x;
    const int lane = tid & 63;
    const int wave = tid >> 6;
    const int wy = wave >> 1, wx = wave & 1;

    // --- T1 XCD-rectangle swizzle (bijective on 32x32)
    const int bid = blockIdx.x;             // 0..1023
    const int xcd = bid & 7;
    const int loc = bid >> 3;               // 0..127
    const int by  = ((xcd >> 2) << 4) + (loc >> 3);   // 0..31
    const int bx  = ((xcd & 3) << 3) + (loc & 7);     // 0..31
    const int rowBase = by * 128;           // a (Zj rows)
    const int colBase = bx * 128;           // b (Zi rows)

    // --- staging: chunk = 8 rows x 128 B = 1 KB = one wave-load (16 B/lane).
    //     lane l -> LDS row (l>>3), physical piece (l&7); needs logical piece
    //     c = (l&7) ^ (row&7) = (l&7) ^ (l>>3) from global.
    //     Wave w stages A rows [32w, 32w+32) and B rows [32w, 32w+32).
    const int srow = lane >> 3;
    const int sc   = (lane & 7) ^ srow;
    const unsigned char* gA = Zj8 + (size_t)(rowBase + 32*wave + srow) * D_DIM + sc*16;
    const unsigned char* gB = Zi8 + (size_t)(colBase + 32*wave + srow) * D_DIM + sc*16;
    unsigned char* sA = lA + wave * 4096;
    unsigned char* sB = lB + wave * 4096;

    // --- fragment addressing (16x16x128): lane l holds row (l&15),
    //     k = (l>>4)*32 + 0..31 -> logical pieces {2g, 2g+1}, g = l>>4.
    //     physical = logical ^ (row&7); row&7 == lane&7 since every fragment
    //     row base (wy*64 + i*16) is a multiple of 8 and row = base + (l&15).
    const int lr16 = lane & 15;
    const int g    = lane >> 4;
    const int o0 = ((((g << 1) + 0) ^ (lane & 7)) << 4);
    const int o1 = ((((g << 1) + 1) ^ (lane & 7)) << 4);
    const unsigned char* fA = lA + (wy * 64 + lr16) * 128;  // + i*16*128
    const unsigned char* fB = lB + (wx * 64 + lr16) * 128;  // + j*16*128

    f32x4 acc[4][4];
    #pragma unroll
    for (int i = 0; i < 4; ++i)
        #pragma unroll
        for (int j = 0; j < 4; ++j)
            acc[i][j] = (f32x4){0.f, 0.f, 0.f, 0.f};

    for (int it = 0; it < 8; ++it) {
        __syncthreads();                    // prior readers done
        const int k0 = it * 128;
        #pragma unroll
        for (int n = 0; n < 4; ++n) {
            gload_lds16(gA + (size_t)(n*8) * D_DIM + k0, sA + n*1024);
            gload_lds16(gB + (size_t)(n*8) * D_DIM + k0, sB + n*1024);
        }
        __syncthreads();                    // staging visible (vmcnt drained)

        i32x8 a0 = read_frag(fA,        o0, o1);
        i32x8 a1 = read_frag(fA + 2048, o0, o1);
        i32x8 a2 = read_frag(fA + 4096, o0, o1);
        i32x8 a3 = read_frag(fA + 6144, o0, o1);
        i32x8 b0 = read_frag(fB,        o0, o1);
        i32x8 b1 = read_frag(fB + 2048, o0, o1);
        i32x8 b2 = read_frag(fB + 4096, o0, o1);
        i32x8 b3 = read_frag(fB + 6144, o0, o1);
        acc[0][0] = MX_MFMA(a0, b0, acc[0][0]);
        acc[0][1] = MX_MFMA(a0, b1, acc[0][1]);
        acc[0][2] = MX_MFMA(a0, b2, acc[0][2]);
        acc[0][3] = MX_MFMA(a0, b3, acc[0][3]);
        acc[1][0] = MX_MFMA(a1, b0, acc[1][0]);
        acc[1][1] = MX_MFMA(a1, b1, acc[1][1]);
        acc[1][2] = MX_MFMA(a1, b2, acc[1][2]);
        acc[1][3] = MX_MFMA(a1, b3, acc[1][3]);
        acc[2][0] = MX_MFMA(a2, b0, acc[2][0]);
        acc[2][1] = MX_MFMA(a2, b1, acc[2][1]);
        acc[2][2] = MX_MFMA(a2, b2, acc[2][2]);
        acc[2][3] = MX_MFMA(a2, b3, acc[2][3]);
        acc[3][0] = MX_MFMA(a3, b0, acc[3][0]);
        acc[3][1] = MX_MFMA(a3, b1, acc[3][1]);
        acc[3][2] = MX_MFMA(a3, b2, acc[3][2]);
        acc[3][3] = MX_MFMA(a3, b3, acc[3][3]);
    }

    // --- fused epilogue; 16x16 C layout: col=lane&15, row=(lane>>4)*4+reg
    //     (round-0-verified mapping)
    float neg = 0.f, pos = 0.f;
    const int bc = colBase + wx * 64 + lr16;
    #pragma unroll
    for (int i = 0; i < 4; ++i) {
        const int abase = rowBase + wy * 64 + i * 16 + g * 4;
        #pragma unroll
        for (int j = 0; j < 4; ++j) {
            const int b = bc + j * 16;
            #pragma unroll
            for (int r = 0; r < 4; ++r) {
                const float x = acc[i][j][r] * INV_S2 - TEMP;   // sim - T
                if (abase + r == b) pos += __logf(1.0f + __expf(-x));
                else                neg += __logf(1.0f + __expf(x));
            }
        }
    }
    #pragma unroll
    for (int o = 32; o > 0; o >>= 1) {
        neg += __shfl_down(neg, o, 64);
        pos += __shfl_down(pos, o, 64);
    }
    if (lane == 0) { rn[wave] = neg; rp[wave] = pos; }
    __syncthreads();
    if (tid == 0) {
        atomicAdd(&w[1], rn[0] + rn[1] + rn[2] + rn[3]);
        if (bx == by)                                    // tile holding diagonal
            atomicAdd(&w[0], rp[0] + rp[1] + rp[2] + rp[3]);
        __threadfence();
        unsigned int done = atomicAdd(((unsigned int*)w) + 2, 1u);
        if (done == gridDim.x - 1) {                     // last block finalizes
            const float psum = atomicAdd(&w[0], 0.0f);
            const float nsum = atomicAdd(&w[1], 0.0f);
            out[0] = 0.5f * (psum / (float)B_ROWS)
                   + 0.5f * (nsum / ((float)B_ROWS * (float)(B_ROWS - 1)));
        }
    }
}

extern "C" void kernel_launch(void* const* d_in, const int* in_sizes, int n_in,
                              void* d_out, int out_size, void* d_ws, size_t ws_size,
                              hipStream_t stream) {
    const float* emb_i = (const float*)d_in[0];
    const float* emb_j = (const float*)d_in[1];
    float* w = (float*)d_ws;
    unsigned char* Zi8 = (unsigned char*)(w + 16);
    unsigned char* Zj8 = Zi8 + (size_t)B_ROWS * D_DIM;
    float* out = (float*)d_out;

    norm_cast_kernel<<<2 * B_ROWS / 4, 256, 0, stream>>>(emb_i, emb_j, Zi8, Zj8, w);
    simloss_mfma_mxfp8_kernel<<<1024, 256, 0, stream>>>(Zi8, Zj8, w, out);
}